// Round 12
// baseline (513.570 us; speedup 1.0000x reference)
//
#include <hip/hip_runtime.h>
#include <stdint.h>
#include <math.h>

#define BG 64
#define NG 1024
#define KK 16
#define CC 128
#define NNODE (BG * NG)          // 65536
#define NSOFT (BG * NG * KK)     // 1048576
#define FEPS 1e-20f

__host__ __device__ __forceinline__ uint32_t rotl32u(uint32_t x, int r) {
  return (x << r) | (x >> (32 - r));
}

// Threefry-2x32, 20 rounds, exactly as jax/_src/prng.py (partitionable mode)
__host__ __device__ __forceinline__ void tf2x32(uint32_t k0, uint32_t k1,
                                                uint32_t x0, uint32_t x1,
                                                uint32_t &o0, uint32_t &o1) {
  uint32_t k2 = k0 ^ k1 ^ 0x1BD11BDAu;
  x0 += k0; x1 += k1;
#define TFR(r) { x0 += x1; x1 = rotl32u(x1, r); x1 ^= x0; }
  TFR(13) TFR(15) TFR(26) TFR(6)
  x0 += k1; x1 += k2 + 1u;
  TFR(17) TFR(29) TFR(16) TFR(24)
  x0 += k2; x1 += k0 + 2u;
  TFR(13) TFR(15) TFR(26) TFR(6)
  x0 += k0; x1 += k1 + 3u;
  TFR(17) TFR(29) TFR(16) TFR(24)
  x0 += k1; x1 += k2 + 4u;
  TFR(13) TFR(15) TFR(26) TFR(6)
  x0 += k2; x1 += k0 + 5u;
#undef TFR
  o0 = x0; o1 = x1;
}

// jax.random.uniform element m (threefry_partitionable: counter hi=0, lo=m)
__device__ __forceinline__ float jax_uniform01(uint32_t ka, uint32_t kb, uint32_t m) {
  uint32_t o0, o1;
  tf2x32(ka, kb, 0u, m, o0, o1);
  uint32_t bits = o0 ^ o1;
  float f = __uint_as_float((bits >> 9) | 0x3f800000u) - 1.0f;
  return fmaxf(f, 0.0f);
}

#define LDS_WAIT() asm volatile("s_waitcnt lgkmcnt(0)" ::: "memory")

// ---- h = x @ W1 + b1 (+ fused per-block BN partial sums) ------------------
__global__ __launch_bounds__(256) void k_gemm1(const float* __restrict__ x,
                                               const float* __restrict__ W1,
                                               const float* __restrict__ b1,
                                               float* __restrict__ h,
                                               float* __restrict__ p1,
                                               float* __restrict__ p2) {
  __shared__ __align__(16) float xs[64 * 128];   // 32 KB (reused for reduce)
  const int t = threadIdx.x;
  const size_t blockBase = (size_t)blockIdx.x * (64 * 128);
  #pragma unroll
  for (int j = 0; j < 32; ++j) xs[t + j * 256] = x[blockBase + t + j * 256];
  __syncthreads();
  const int c = t & 127;
  const int rg = t >> 7;
  float acc[32];
  #pragma unroll
  for (int j = 0; j < 32; ++j) acc[j] = 0.f;
  const float* xrow = &xs[rg * 32 * 128];
  for (int k4 = 0; k4 < 128; k4 += 4) {
    const float w0 = W1[(size_t)(k4 + 0) * 128 + c];
    const float w1 = W1[(size_t)(k4 + 1) * 128 + c];
    const float w2 = W1[(size_t)(k4 + 2) * 128 + c];
    const float w3 = W1[(size_t)(k4 + 3) * 128 + c];
    #pragma unroll
    for (int j = 0; j < 32; ++j) {
      const float4 xv = *(const float4*)&xrow[j * 128 + k4];
      acc[j] = fmaf(xv.x, w0, acc[j]);
      acc[j] = fmaf(xv.y, w1, acc[j]);
      acc[j] = fmaf(xv.z, w2, acc[j]);
      acc[j] = fmaf(xv.w, w3, acc[j]);
    }
  }
  const float bb = b1[c];
  float s1 = 0.f, s2 = 0.f;
  #pragma unroll
  for (int j = 0; j < 32; ++j) {
    const float v = acc[j] + bb;
    h[blockBase + (size_t)(rg * 32 + j) * 128 + c] = v;
    s1 += v;
    s2 = fmaf(v, v, s2);
  }
  __syncthreads();
  float* r1 = xs;
  float* r2 = xs + 256;
  r1[rg * 128 + c] = s1;
  r2[rg * 128 + c] = s2;
  __syncthreads();
  if (t < 128) {
    p1[(size_t)t * 1024 + blockIdx.x] = r1[t] + r1[128 + t];
  } else {
    const int cc = t - 128;
    p2[(size_t)cc * 1024 + blockIdx.x] = r2[cc] + r2[128 + cc];
  }
}

// ---- finalize BN ----------------------------------------------------------
__global__ __launch_bounds__(256) void k_bn_final(const float* __restrict__ p1,
                                                  const float* __restrict__ p2,
                                                  const float* __restrict__ gamma,
                                                  const float* __restrict__ beta,
                                                  float* __restrict__ scale,
                                                  float* __restrict__ shift) {
  const int c = blockIdx.x, t = threadIdx.x;
  const float* q1 = p1 + (size_t)c * 1024;
  const float* q2 = p2 + (size_t)c * 1024;
  float a1 = q1[t] + q1[t + 256] + q1[t + 512] + q1[t + 768];
  float a2 = q2[t] + q2[t + 256] + q2[t + 512] + q2[t + 768];
  __shared__ float r1[256], r2[256];
  r1[t] = a1; r2[t] = a2;
  __syncthreads();
  for (int o = 128; o > 0; o >>= 1) {
    if (t < o) { r1[t] += r1[t + o]; r2[t] += r2[t + o]; }
    __syncthreads();
  }
  if (t == 0) {
    const float mu = r1[0] * (1.0f / NNODE);
    float var = r2[0] * (1.0f / NNODE) - mu * mu;
    var = fmaxf(var, 0.f);
    const float sc = gamma[c] / sqrtf(var + 1e-5f);
    scale[c] = sc;
    shift[c] = beta[c] - mu * sc;
  }
}

// ---- normalize+relu + @W2 + b2 + 0.001*uniform(k1) -> plane-major et2 -----
// et2 layout: plane p in [0,5): et2[p*NNODE + node] = (e[node][2p], e[node][2p+1])
__global__ __launch_bounds__(256) void k_emb(const float* __restrict__ h,
                                             const float* __restrict__ scale,
                                             const float* __restrict__ shift,
                                             const float* __restrict__ W2,
                                             const float* __restrict__ b2,
                                             float2* __restrict__ et2,
                                             uint32_t ka, uint32_t kb) {
  __shared__ __align__(16) float hn[64 * 132];
  __shared__ float et[64 * 10];
  const int t = threadIdx.x;
  const int rowBase = blockIdx.x * 64;
  {
    const int c = t & 127;
    const float sc = scale[c], sh = shift[c];
    #pragma unroll
    for (int j = 0; j < 32; ++j) {
      const int r = (t >> 7) + j * 2;
      const float v = fmaf(h[(size_t)(rowBase + r) * 128 + c], sc, sh);
      hn[r * 132 + c] = fmaxf(v, 0.f);
    }
  }
  __syncthreads();
  #pragma unroll
  for (int j = 0; j < 3; ++j) {
    const int o = t + j * 256;
    if (o < 640) {
      const int r = o / 10;
      const int col = o - r * 10;
      float acc = 0.f;
      for (int k4 = 0; k4 < 128; k4 += 4) {
        const float4 hv = *(const float4*)&hn[r * 132 + k4];
        acc = fmaf(hv.x, W2[(k4 + 0) * 10 + col], acc);
        acc = fmaf(hv.y, W2[(k4 + 1) * 10 + col], acc);
        acc = fmaf(hv.z, W2[(k4 + 2) * 10 + col], acc);
        acc = fmaf(hv.w, W2[(k4 + 3) * 10 + col], acc);
      }
      acc += b2[col];
      const uint32_t m = (uint32_t)(rowBase + r) * 10u + (uint32_t)col;
      const float u = jax_uniform01(ka, kb, m);
      et[r * 10 + col] = acc + u * 0.001f;
    }
  }
  __syncthreads();
  // write plane-major pairs: consecutive r -> coalesced 8B stores
  if (t < 320) {
    const int r = t & 63, p = t >> 6;
    et2[(size_t)p * NNODE + rowBase + r] =
        make_float2(et[r * 10 + 2 * p], et[r * 10 + 2 * p + 1]);
  }
}

// ---- soft edges: 4 waves/block, VGPR budget 128, coalesced global reads ---
__global__ __launch_bounds__(256, 4) void k_soft(const float2* __restrict__ et2,
                                                 const float* __restrict__ tsc,
                                                 float* __restrict__ out,
                                                 uint32_t ka, uint32_t kb) {
  __shared__ float    cv[4][48];
  __shared__ int      cidx[4][48];
  __shared__ uint32_t cnt[4];
  __shared__ float    o16v[4][16];
  __shared__ int      o16i[4][16];

  const int t = threadIdx.x, lane = t & 63, w = t >> 6;
  const int node = blockIdx.x * 4 + w;
  const int b = node >> 10;
  const int jt = node & (NG - 1);
  const int gb = b << 10;                        // graph base node
  const float negt = -tsc[0];

  if (lane == 0) cnt[w] = 0u;
  LDS_WAIT();

  float ej[10];
  #pragma unroll
  for (int p = 0; p < 5; ++p) {
    const float2 a = et2[(size_t)p * NNODE + node];
    ej[2 * p] = a.x; ej[2 * p + 1] = a.y;
  }

  // phase 1: 16 scores/lane; 4 interleaved threefry chains; coalesced loads
  float vv[16];
  const uint32_t mL = ((uint32_t)b << 20) + ((uint32_t)lane << 10) + (uint32_t)jt;
  const uint32_t kxa = ka, kxb = kb;
  const uint32_t kxc = ka ^ kb ^ 0x1BD11BDAu;

#define DIST(ACC, S) { \
    const float2 r0 = et2[0 * (size_t)NNODE + gb + (S)]; \
    const float2 r1 = et2[1 * (size_t)NNODE + gb + (S)]; \
    const float2 r2 = et2[2 * (size_t)NNODE + gb + (S)]; \
    const float2 r3 = et2[3 * (size_t)NNODE + gb + (S)]; \
    const float2 r4 = et2[4 * (size_t)NNODE + gb + (S)]; \
    float dd; \
    dd = ej[0] - r0.x; ACC = dd * dd; \
    dd = ej[1] - r0.y; ACC = fmaf(dd, dd, ACC); \
    dd = ej[2] - r1.x; ACC = fmaf(dd, dd, ACC); \
    dd = ej[3] - r1.y; ACC = fmaf(dd, dd, ACC); \
    dd = ej[4] - r2.x; ACC = fmaf(dd, dd, ACC); \
    dd = ej[5] - r2.y; ACC = fmaf(dd, dd, ACC); \
    dd = ej[6] - r3.x; ACC = fmaf(dd, dd, ACC); \
    dd = ej[7] - r3.y; ACC = fmaf(dd, dd, ACC); \
    dd = ej[8] - r4.x; ACC = fmaf(dd, dd, ACC); \
    dd = ej[9] - r4.y; ACC = fmaf(dd, dd, ACC); }

#define TFR4(r) { \
    xA0 += xA1; xA1 = rotl32u(xA1, r); xA1 ^= xA0; \
    xB0 += xB1; xB1 = rotl32u(xB1, r); xB1 ^= xB0; \
    xC0 += xC1; xC1 = rotl32u(xC1, r); xC1 ^= xC0; \
    xD0 += xD1; xD1 = rotl32u(xD1, r); xD1 ^= xD0; }
#define INJ4(A, B) { \
    xA0 += (A); xA1 += (B); \
    xB0 += (A); xB1 += (B); \
    xC0 += (A); xC1 += (B); \
    xD0 += (A); xD1 += (B); }

#define TAIL(ACC, X0, X1, ST) { \
    const uint32_t bits = (X0) ^ (X1); \
    float uu = __uint_as_float((bits >> 9) | 0x3f800000u) - 1.0f; \
    uu = fmaxf(uu, 0.0f); \
    const float dist = sqrtf(ACC); \
    const float d2 = dist * dist; \
    const float p = __expf(negt * d2); \
    const float li = __logf(uu + FEPS); \
    const float g = -__logf(FEPS - li); \
    vv[ST] = __logf(p + FEPS) + g; }

  #pragma unroll
  for (int g4 = 0; g4 < 4; ++g4) {
    const int sA = (g4 * 4 + 0) * 64 + lane;
    const int sB = (g4 * 4 + 1) * 64 + lane;
    const int sC = (g4 * 4 + 2) * 64 + lane;
    const int sD = (g4 * 4 + 3) * 64 + lane;
    float aA, aB, aC, aD;
    DIST(aA, sA)
    DIST(aB, sB)
    DIST(aC, sC)
    DIST(aD, sD)
    uint32_t xA0 = kxa, xA1 = (mL + (uint32_t)((g4 * 4 + 0) << 16)) + kxb;
    uint32_t xB0 = kxa, xB1 = (mL + (uint32_t)((g4 * 4 + 1) << 16)) + kxb;
    uint32_t xC0 = kxa, xC1 = (mL + (uint32_t)((g4 * 4 + 2) << 16)) + kxb;
    uint32_t xD0 = kxa, xD1 = (mL + (uint32_t)((g4 * 4 + 3) << 16)) + kxb;
    TFR4(13) TFR4(15) TFR4(26) TFR4(6)
    INJ4(kxb, kxc + 1u)
    TFR4(17) TFR4(29) TFR4(16) TFR4(24)
    INJ4(kxc, kxa + 2u)
    TFR4(13) TFR4(15) TFR4(26) TFR4(6)
    INJ4(kxa, kxb + 3u)
    TFR4(17) TFR4(29) TFR4(16) TFR4(24)
    INJ4(kxb, kxc + 4u)
    TFR4(13) TFR4(15) TFR4(26) TFR4(6)
    INJ4(kxc, kxa + 5u)
    TAIL(aA, xA0, xA1, g4 * 4 + 0)
    TAIL(aB, xB0, xB1, g4 * 4 + 1)
    TAIL(aC, xC0, xC1, g4 * 4 + 2)
    TAIL(aD, xD0, xD1, g4 * 4 + 3)
  }
#undef DIST
#undef TFR4
#undef INJ4
#undef TAIL

  // phase 2: ballot binary search for tau with count(>=tau) >= 16
  float lo = -51.0f, hi = 17.0f;
  #pragma unroll 1
  for (int it = 0; it < 24; ++it) {
    const float mid = 0.5f * (lo + hi);
    int c = 0;
    #pragma unroll
    for (int st = 0; st < 16; ++st)
      c += (int)__popcll(__ballot(vv[st] >= mid));
    if (c >= 16) lo = mid; else hi = mid;
  }
  const float tau = lo;

  // phase 3: collect candidates (v >= tau); ~16-48 appends per wave
  #pragma unroll
  for (int st = 0; st < 16; ++st) {
    if (vv[st] >= tau) {
      const uint32_t pos = atomicAdd(&cnt[w], 1u);
      if (pos < 48u) { cv[w][pos] = vv[st]; cidx[w][pos] = st * 64 + lane; }
    }
  }
  LDS_WAIT();

  // phase 4: exact rank (fixed-48 unrolled, predicated -> pipelined LDS reads)
  const int C = min((int)cnt[w], 48);
  const float mvv = (lane < C) ? cv[w][lane] : 0.f;
  const int   mii = (lane < C) ? cidx[w][lane] : 0;
  int rank = 0;
  #pragma unroll
  for (int j = 0; j < 48; ++j) {
    const float vj = cv[w][j];
    const int ij = cidx[w][j];
    const bool act = (j < C) && (vj > mvv || (vj == mvv && ij < mii));
    rank += act ? 1 : 0;
  }
  if (lane < C && rank < 16) { o16v[w][rank] = mvv; o16i[w][rank] = mii; }
  LDS_WAIT();

  // phase 5: softmax / max-normalize (literal ref op order), write outputs
  if (lane < 16) {
    const float vq = o16v[w][lane];
    const float m0 = o16v[w][0];
    float uex = __expf(vq - m0);
    float ss = uex;
    #pragma unroll
    for (int off = 1; off < 16; off <<= 1) ss += __shfl_xor(ss, off, 16);
    const float u0 = __shfl(uex, 0, 16);
    const float s0v = u0 / ss;
    const float sv = uex / ss;
    const float o = sv / s0v;
    const size_t base = (size_t)node * KK + lane;
    const float tgtf = (float)node;
    const float srcf = (float)(gb + o16i[w][lane]);
    out[base] = o;                                  // vals
    out[(size_t)NSOFT + base] = srcf;               // soft_idx row0
    out[2 * (size_t)NSOFT + base] = tgtf;           // soft_idx row1
    out[3 * (size_t)NSOFT + base] = srcf;           // edge row0 (soft)
    out[5 * (size_t)NSOFT + base] = tgtf;           // edge row1 (soft)
  }
}

// ---- knn edges: 1024-thread blocks; ballot binary-search select -----------
__global__ __launch_bounds__(1024, 4) void k_knn(const float* __restrict__ pos,
                                                 float* __restrict__ out) {
  __shared__ float    pls[3 * NG];
  __shared__ float    cv[16][48];
  __shared__ int      cidx[16][48];
  __shared__ uint32_t cnt[16];
  __shared__ int      o16i[16][16];

  const int t = threadIdx.x, lane = t & 63, w = t >> 6;
  const int node = blockIdx.x * 16 + w;
  const int b = blockIdx.x >> 6;
  const int it = node & (NG - 1);
  const float* pg = pos + (size_t)b * (NG * 3);

  if (lane == 0) cnt[w] = 0u;

  for (int f = t; f < 3072; f += 1024) {
    const int r = f / 3, d = f - r * 3;
    pls[d * NG + r] = pg[f];
  }
  __syncthreads();

  const float px = pls[0 * NG + it];
  const float py = pls[1 * NG + it];
  const float pz = pls[2 * NG + it];

  float vv[16];
  #pragma unroll
  for (int st = 0; st < 16; ++st) {
    const int s = st * 64 + lane;
    const float dx = px - pls[0 * NG + s];
    const float dy = py - pls[1 * NG + s];
    const float dz = pz - pls[2 * NG + s];
    float d2 = dx * dx;
    d2 = fmaf(dy, dy, d2);
    d2 = fmaf(dz, dz, d2);
    if (s == it) d2 += 1e10f;            // exclude self
    vv[st] = -d2;                        // top_k(-d2)
  }

  float lo = -70.0f, hi = 1.0f;
  #pragma unroll 1
  for (int bs = 0; bs < 26; ++bs) {
    const float mid = 0.5f * (lo + hi);
    int c = 0;
    #pragma unroll
    for (int st = 0; st < 16; ++st)
      c += (int)__popcll(__ballot(vv[st] >= mid));
    if (c >= 16) lo = mid; else hi = mid;
  }
  const float tau = lo;

  #pragma unroll
  for (int st = 0; st < 16; ++st) {
    if (vv[st] >= tau) {
      const uint32_t pos = atomicAdd(&cnt[w], 1u);
      if (pos < 48u) { cv[w][pos] = vv[st]; cidx[w][pos] = st * 64 + lane; }
    }
  }
  LDS_WAIT();

  const int C = min((int)cnt[w], 48);
  const float mvv = (lane < C) ? cv[w][lane] : 0.f;
  const int   mii = (lane < C) ? cidx[w][lane] : 0;
  int rank = 0;
  #pragma unroll
  for (int j = 0; j < 48; ++j) {
    const float vj = cv[w][j];
    const int ij = cidx[w][j];
    const bool act = (j < C) && (vj > mvv || (vj == mvv && ij < mii));
    rank += act ? 1 : 0;
  }
  if (lane < C && rank < 16) o16i[w][rank] = mii;
  LDS_WAIT();

  if (lane < 16) {
    const size_t base = (size_t)node * KK + lane;
    out[4 * (size_t)NSOFT + base] = (float)(b * NG + o16i[w][lane]);
    out[6 * (size_t)NSOFT + base] = (float)node;
  }
}

extern "C" void kernel_launch(void* const* d_in, const int* in_sizes, int n_in,
                              void* d_out, int out_size, void* d_ws, size_t ws_size,
                              hipStream_t stream) {
  const float* x     = (const float*)d_in[0];
  const float* pos   = (const float*)d_in[1];
  const float* W1    = (const float*)d_in[2];
  const float* b1    = (const float*)d_in[3];
  const float* gamma = (const float*)d_in[4];
  const float* beta  = (const float*)d_in[5];
  const float* W2    = (const float*)d_in[6];
  const float* b2    = (const float*)d_in[7];
  const float* t     = (const float*)d_in[8];
  float* out = (float*)d_out;

  float* ws    = (float*)d_ws;
  float* h     = ws;                                  // 65536*128
  float2* et2  = (float2*)(h + (size_t)NNODE * CC);   // 5*65536 float2
  float* p1    = (float*)(et2 + 5 * (size_t)NNODE);   // 128*1024
  float* p2    = p1 + 128 * 1024;                     // 128*1024
  float* scale = p2 + 128 * 1024;                     // 128
  float* shift = scale + CC;                          // 128

  // key(42) = (0,42); partitionable split -> k1, k2
  uint32_t k1a, k1b, k2a, k2b;
  tf2x32(0u, 42u, 0u, 0u, k1a, k1b);
  tf2x32(0u, 42u, 0u, 1u, k2a, k2b);

  k_gemm1<<<dim3(NNODE / 64), dim3(256), 0, stream>>>(x, W1, b1, h, p1, p2);
  k_bn_final<<<dim3(CC), dim3(256), 0, stream>>>(p1, p2, gamma, beta, scale, shift);
  k_emb<<<dim3(NNODE / 64), dim3(256), 0, stream>>>(h, scale, shift, W2, b2, et2, k1a, k1b);
  k_knn<<<dim3(NNODE / 16), dim3(1024), 0, stream>>>(pos, out);
  k_soft<<<dim3(NNODE / 4), dim3(256), 0, stream>>>(et2, t, out, k2a, k2b);
}

// Round 13
// 421.695 us; speedup vs baseline: 1.2179x; 1.2179x over previous
//
#include <hip/hip_runtime.h>
#include <stdint.h>
#include <math.h>

#define BG 64
#define NG 1024
#define KK 16
#define CC 128
#define NNODE (BG * NG)          // 65536
#define NSOFT (BG * NG * KK)     // 1048576
#define FEPS 1e-20f

__host__ __device__ __forceinline__ uint32_t rotl32u(uint32_t x, int r) {
  return (x << r) | (x >> (32 - r));
}

// Threefry-2x32, 20 rounds, exactly as jax/_src/prng.py (partitionable mode)
__host__ __device__ __forceinline__ void tf2x32(uint32_t k0, uint32_t k1,
                                                uint32_t x0, uint32_t x1,
                                                uint32_t &o0, uint32_t &o1) {
  uint32_t k2 = k0 ^ k1 ^ 0x1BD11BDAu;
  x0 += k0; x1 += k1;
#define TFR(r) { x0 += x1; x1 = rotl32u(x1, r); x1 ^= x0; }
  TFR(13) TFR(15) TFR(26) TFR(6)
  x0 += k1; x1 += k2 + 1u;
  TFR(17) TFR(29) TFR(16) TFR(24)
  x0 += k2; x1 += k0 + 2u;
  TFR(13) TFR(15) TFR(26) TFR(6)
  x0 += k0; x1 += k1 + 3u;
  TFR(17) TFR(29) TFR(16) TFR(24)
  x0 += k1; x1 += k2 + 4u;
  TFR(13) TFR(15) TFR(26) TFR(6)
  x0 += k2; x1 += k0 + 5u;
#undef TFR
  o0 = x0; o1 = x1;
}

// jax.random.uniform element m (threefry_partitionable: counter hi=0, lo=m)
__device__ __forceinline__ float jax_uniform01(uint32_t ka, uint32_t kb, uint32_t m) {
  uint32_t o0, o1;
  tf2x32(ka, kb, 0u, m, o0, o1);
  uint32_t bits = o0 ^ o1;
  float f = __uint_as_float((bits >> 9) | 0x3f800000u) - 1.0f;
  return fmaxf(f, 0.0f);
}

// Linear-quantized bin; identical computation in histogram and collect phases.
// Soft logits: v in [-49.9, 16.7]  -> LO=-50, span 67
__device__ __forceinline__ int vbin_soft(float v) {
  float fb = (v + 50.0f) * (256.0f / 67.0f);
  fb = fminf(fmaxf(fb, 0.0f), 255.0f);
  return (int)fb;
}
// KNN scores: v = -d2 in [-inf, 0] -> LO=-64, span 64 (d2>64 clamps to bin 0)
__device__ __forceinline__ int vbin_knn(float v) {
  float fb = (v + 64.0f) * 4.0f;
  fb = fminf(fmaxf(fb, 0.0f), 255.0f);
  return (int)fb;
}

#define LDS_WAIT() asm volatile("s_waitcnt lgkmcnt(0)" ::: "memory")

// ---- h = x @ W1 + b1 (+ fused per-block BN partial sums) ------------------
__global__ __launch_bounds__(256) void k_gemm1(const float* __restrict__ x,
                                               const float* __restrict__ W1,
                                               const float* __restrict__ b1,
                                               float* __restrict__ h,
                                               float* __restrict__ p1,
                                               float* __restrict__ p2) {
  __shared__ __align__(16) float xs[64 * 128];   // 32 KB (reused for reduce)
  const int t = threadIdx.x;
  const size_t blockBase = (size_t)blockIdx.x * (64 * 128);
  #pragma unroll
  for (int j = 0; j < 32; ++j) xs[t + j * 256] = x[blockBase + t + j * 256];
  __syncthreads();
  const int c = t & 127;
  const int rg = t >> 7;
  float acc[32];
  #pragma unroll
  for (int j = 0; j < 32; ++j) acc[j] = 0.f;
  const float* xrow = &xs[rg * 32 * 128];
  for (int k4 = 0; k4 < 128; k4 += 4) {
    const float w0 = W1[(size_t)(k4 + 0) * 128 + c];
    const float w1 = W1[(size_t)(k4 + 1) * 128 + c];
    const float w2 = W1[(size_t)(k4 + 2) * 128 + c];
    const float w3 = W1[(size_t)(k4 + 3) * 128 + c];
    #pragma unroll
    for (int j = 0; j < 32; ++j) {
      const float4 xv = *(const float4*)&xrow[j * 128 + k4];
      acc[j] = fmaf(xv.x, w0, acc[j]);
      acc[j] = fmaf(xv.y, w1, acc[j]);
      acc[j] = fmaf(xv.z, w2, acc[j]);
      acc[j] = fmaf(xv.w, w3, acc[j]);
    }
  }
  const float bb = b1[c];
  float s1 = 0.f, s2 = 0.f;
  #pragma unroll
  for (int j = 0; j < 32; ++j) {
    const float v = acc[j] + bb;
    h[blockBase + (size_t)(rg * 32 + j) * 128 + c] = v;
    s1 += v;
    s2 = fmaf(v, v, s2);
  }
  __syncthreads();
  float* r1 = xs;
  float* r2 = xs + 256;
  r1[rg * 128 + c] = s1;
  r2[rg * 128 + c] = s2;
  __syncthreads();
  if (t < 128) {
    p1[(size_t)t * 1024 + blockIdx.x] = r1[t] + r1[128 + t];
  } else {
    const int cc = t - 128;
    p2[(size_t)cc * 1024 + blockIdx.x] = r2[cc] + r2[128 + cc];
  }
}

// ---- finalize BN ----------------------------------------------------------
__global__ __launch_bounds__(256) void k_bn_final(const float* __restrict__ p1,
                                                  const float* __restrict__ p2,
                                                  const float* __restrict__ gamma,
                                                  const float* __restrict__ beta,
                                                  float* __restrict__ scale,
                                                  float* __restrict__ shift) {
  const int c = blockIdx.x, t = threadIdx.x;
  const float* q1 = p1 + (size_t)c * 1024;
  const float* q2 = p2 + (size_t)c * 1024;
  float a1 = q1[t] + q1[t + 256] + q1[t + 512] + q1[t + 768];
  float a2 = q2[t] + q2[t + 256] + q2[t + 512] + q2[t + 768];
  __shared__ float r1[256], r2[256];
  r1[t] = a1; r2[t] = a2;
  __syncthreads();
  for (int o = 128; o > 0; o >>= 1) {
    if (t < o) { r1[t] += r1[t + o]; r2[t] += r2[t + o]; }
    __syncthreads();
  }
  if (t == 0) {
    const float mu = r1[0] * (1.0f / NNODE);
    float var = r2[0] * (1.0f / NNODE) - mu * mu;
    var = fmaxf(var, 0.f);
    const float sc = gamma[c] / sqrtf(var + 1e-5f);
    scale[c] = sc;
    shift[c] = beta[c] - mu * sc;
  }
}

// ---- normalize+relu (fma) + @W2 + b2 + 0.001*uniform(k1) ------------------
__global__ __launch_bounds__(256) void k_emb(const float* __restrict__ h,
                                             const float* __restrict__ scale,
                                             const float* __restrict__ shift,
                                             const float* __restrict__ W2,
                                             const float* __restrict__ b2,
                                             float* __restrict__ e,
                                             uint32_t ka, uint32_t kb) {
  __shared__ __align__(16) float hn[64 * 132];
  const int t = threadIdx.x;
  const int rowBase = blockIdx.x * 64;
  {
    const int c = t & 127;
    const float sc = scale[c], sh = shift[c];
    #pragma unroll
    for (int j = 0; j < 32; ++j) {
      const int r = (t >> 7) + j * 2;
      const float v = fmaf(h[(size_t)(rowBase + r) * 128 + c], sc, sh);
      hn[r * 132 + c] = fmaxf(v, 0.f);
    }
  }
  __syncthreads();
  #pragma unroll
  for (int j = 0; j < 3; ++j) {
    const int o = t + j * 256;
    if (o < 640) {
      const int r = o / 10;
      const int col = o - r * 10;
      float acc = 0.f;
      for (int k4 = 0; k4 < 128; k4 += 4) {
        const float4 hv = *(const float4*)&hn[r * 132 + k4];
        acc = fmaf(hv.x, W2[(k4 + 0) * 10 + col], acc);
        acc = fmaf(hv.y, W2[(k4 + 1) * 10 + col], acc);
        acc = fmaf(hv.z, W2[(k4 + 2) * 10 + col], acc);
        acc = fmaf(hv.w, W2[(k4 + 3) * 10 + col], acc);
      }
      acc += b2[col];
      const uint32_t m = (uint32_t)(rowBase + r) * 10u + (uint32_t)col;
      const float u = jax_uniform01(ka, kb, m);
      e[(size_t)(rowBase + r) * 10 + col] = acc + u * 0.001f;
    }
  }
}

// ---- soft edges: r4 base + register-double-buffered source prefetch -------
__global__ __launch_bounds__(512, 4) void k_soft(const float* __restrict__ e,
                                                 const float* __restrict__ tsc,
                                                 float* __restrict__ out,
                                                 uint32_t ka, uint32_t kb) {
  __shared__ __align__(16) float2 els2[5 * NG];   // 40 KB transposed planes
  __shared__ uint32_t bins[8][256];               // 8 KB, per-wave
  __shared__ float    cv[8][48];
  __shared__ int      cidx[8][48];
  __shared__ uint32_t cnt[8];
  __shared__ float    o16v[8][16];
  __shared__ int      o16i[8][16];

  const int t = threadIdx.x, lane = t & 63, w = t >> 6;
  const int node = blockIdx.x * 8 + w;
  const int b = blockIdx.x >> 7;                 // 128 blocks per graph
  const int jt = node & (NG - 1);
  const float negt = -tsc[0];
  const float* eg = e + (size_t)b * (NG * 10);

  { uint4 z = {0, 0, 0, 0}; *(uint4*)&bins[w][lane * 4] = z; }
  if (lane == 0) cnt[w] = 0u;

  // stage e transposed into float2 planes
  for (int s = t; s < NG; s += 512) {
    const float2* rp = (const float2*)(eg + (size_t)s * 10);
    els2[0 * NG + s] = rp[0];
    els2[1 * NG + s] = rp[1];
    els2[2 * NG + s] = rp[2];
    els2[3 * NG + s] = rp[3];
    els2[4 * NG + s] = rp[4];
  }
  __syncthreads();

  float ej[10];
  #pragma unroll
  for (int p = 0; p < 5; ++p) {
    const float2 a = els2[p * NG + jt];
    ej[2 * p] = a.x; ej[2 * p + 1] = a.y;
  }

  // phase 1: 16 scores/lane, 2 sources/step; explicit double-buffered
  // register prefetch (buf[ns] loads overlap buf[cs] compute).
  float vv[16];
  const uint32_t mL = ((uint32_t)b << 20) + ((uint32_t)lane << 10) + (uint32_t)jt;
  const uint32_t kxa = ka, kxb = kb;
  const uint32_t kxc = ka ^ kb ^ 0x1BD11BDAu;

  float2 bufA[2][5], bufB[2][5];
  #pragma unroll
  for (int p = 0; p < 5; ++p) {
    bufA[0][p] = els2[p * NG + lane];
    bufB[0][p] = els2[p * NG + 64 + lane];
  }

#define DISTB(ACC, BUF, SI) { \
    float dd; \
    dd = ej[0] - BUF[SI][0].x; ACC = dd * dd; \
    dd = ej[1] - BUF[SI][0].y; ACC = fmaf(dd, dd, ACC); \
    dd = ej[2] - BUF[SI][1].x; ACC = fmaf(dd, dd, ACC); \
    dd = ej[3] - BUF[SI][1].y; ACC = fmaf(dd, dd, ACC); \
    dd = ej[4] - BUF[SI][2].x; ACC = fmaf(dd, dd, ACC); \
    dd = ej[5] - BUF[SI][2].y; ACC = fmaf(dd, dd, ACC); \
    dd = ej[6] - BUF[SI][3].x; ACC = fmaf(dd, dd, ACC); \
    dd = ej[7] - BUF[SI][3].y; ACC = fmaf(dd, dd, ACC); \
    dd = ej[8] - BUF[SI][4].x; ACC = fmaf(dd, dd, ACC); \
    dd = ej[9] - BUF[SI][4].y; ACC = fmaf(dd, dd, ACC); }

#define TFR2(r) { \
    xA0 += xA1; xA1 = rotl32u(xA1, r); xA1 ^= xA0; \
    xB0 += xB1; xB1 = rotl32u(xB1, r); xB1 ^= xB0; }
#define INJ2(A, B) { \
    xA0 += (A); xA1 += (B); \
    xB0 += (A); xB1 += (B); }

#define TAIL(ACC, X0, X1, ST) { \
    const uint32_t bits = (X0) ^ (X1); \
    float uu = __uint_as_float((bits >> 9) | 0x3f800000u) - 1.0f; \
    uu = fmaxf(uu, 0.0f); \
    const float dist = sqrtf(ACC); \
    const float d2 = dist * dist; \
    const float p = __expf(negt * d2); \
    const float li = __logf(uu + FEPS); \
    const float g = -__logf(FEPS - li); \
    const float v = __logf(p + FEPS) + g; \
    vv[ST] = v; \
    atomicAdd(&bins[w][vbin_soft(v)], 1u); }

  #pragma unroll
  for (int k = 0; k < 8; ++k) {
    const int cs = k & 1, ns = cs ^ 1;
    if (k < 7) {                       // prefetch next 2 source rows
      const int sa = (2 * k + 2) * 64 + lane;
      const int sb = (2 * k + 3) * 64 + lane;
      #pragma unroll
      for (int p = 0; p < 5; ++p) {
        bufA[ns][p] = els2[p * NG + sa];
        bufB[ns][p] = els2[p * NG + sb];
      }
    }
    float aA, aB;
    DISTB(aA, bufA, cs)
    DISTB(aB, bufB, cs)
    uint32_t xA0 = kxa, xA1 = (mL + (uint32_t)((2 * k + 0) << 16)) + kxb;
    uint32_t xB0 = kxa, xB1 = (mL + (uint32_t)((2 * k + 1) << 16)) + kxb;
    TFR2(13) TFR2(15) TFR2(26) TFR2(6)
    INJ2(kxb, kxc + 1u)
    TFR2(17) TFR2(29) TFR2(16) TFR2(24)
    INJ2(kxc, kxa + 2u)
    TFR2(13) TFR2(15) TFR2(26) TFR2(6)
    INJ2(kxa, kxb + 3u)
    TFR2(17) TFR2(29) TFR2(16) TFR2(24)
    INJ2(kxb, kxc + 4u)
    TFR2(13) TFR2(15) TFR2(26) TFR2(6)
    INJ2(kxc, kxa + 5u)
    TAIL(aA, xA0, xA1, 2 * k + 0)
    TAIL(aB, xB0, xB1, 2 * k + 1)
  }
#undef DISTB
#undef TFR2
#undef INJ2
#undef TAIL
  LDS_WAIT();

  // phase 2: wave suffix-scan of 256 bins -> threshold bin B (= bin of v16)
  const uint4 c4 = *(const uint4*)&bins[w][lane * 4];
  const uint32_t lsum = c4.x + c4.y + c4.z + c4.w;
  uint32_t xs = lsum;
  #pragma unroll
  for (int off = 1; off < 64; off <<= 1) {
    uint32_t tt = (uint32_t)__shfl_down((int)xs, off, 64);
    if (lane + off < 64) xs += tt;
  }
  const uint32_t after = xs - lsum;
  const uint32_t s3 = c4.w + after;
  const uint32_t s2 = c4.z + s3;
  const uint32_t s1 = c4.y + s2;
  const uint32_t s0 = c4.x + s1;
  int localB = -1;
  if (s3 >= 16u) localB = lane * 4 + 3;
  else if (s2 >= 16u) localB = lane * 4 + 2;
  else if (s1 >= 16u) localB = lane * 4 + 1;
  else if (s0 >= 16u) localB = lane * 4 + 0;
  const unsigned long long msk = __ballot(localB >= 0);
  const int hl = 63 - __builtin_clzll(msk);
  const int B = __shfl(localB, hl, 64);

  // phase 3: collect candidates (bin >= B)
  #pragma unroll
  for (int st = 0; st < 16; ++st) {
    if (vbin_soft(vv[st]) >= B) {
      const uint32_t pos = atomicAdd(&cnt[w], 1u);
      if (pos < 48u) { cv[w][pos] = vv[st]; cidx[w][pos] = st * 64 + lane; }
    }
  }
  LDS_WAIT();

  // phase 4: exact rank by count with (v desc, idx asc) = jax top_k order
  int C = (int)cnt[w]; if (C > 48) C = 48;
  const float mvv = (lane < C) ? cv[w][lane] : 0.f;
  const int   mii = (lane < C) ? cidx[w][lane] : 0;
  int rank = 0;
  for (int j = 0; j < C; ++j) {
    const float vj = cv[w][j];
    const int ij = cidx[w][j];
    if (vj > mvv || (vj == mvv && ij < mii)) ++rank;
  }
  if (lane < C && rank < 16) { o16v[w][rank] = mvv; o16i[w][rank] = mii; }
  LDS_WAIT();

  // phase 5: softmax / max-normalize (literal ref op order), write outputs
  if (lane < 16) {
    const float vq = o16v[w][lane];
    const float m0 = o16v[w][0];
    float uex = __expf(vq - m0);
    float ss = uex;
    #pragma unroll
    for (int off = 1; off < 16; off <<= 1) ss += __shfl_xor(ss, off, 16);
    const float u0 = __shfl(uex, 0, 16);
    const float s0v = u0 / ss;
    const float sv = uex / ss;
    const float o = sv / s0v;
    const size_t base = (size_t)node * KK + lane;
    const float tgtf = (float)node;
    const float srcf = (float)(b * NG + o16i[w][lane]);
    out[base] = o;                                  // vals
    out[(size_t)NSOFT + base] = srcf;               // soft_idx row0
    out[2 * (size_t)NSOFT + base] = tgtf;           // soft_idx row1
    out[3 * (size_t)NSOFT + base] = srcf;           // edge row0 (soft)
    out[5 * (size_t)NSOFT + base] = tgtf;           // edge row1 (soft)
  }
}

// ---- knn edges: pos staged transposed in LDS; histogram select ------------
__global__ __launch_bounds__(512) void k_knn(const float* __restrict__ pos,
                                             float* __restrict__ out) {
  __shared__ float    pls[3 * NG];
  __shared__ uint32_t bins[8][256];
  __shared__ float    cv[8][48];
  __shared__ int      cidx[8][48];
  __shared__ uint32_t cnt[8];
  __shared__ int      o16i[8][16];

  const int t = threadIdx.x, lane = t & 63, w = t >> 6;
  const int node = blockIdx.x * 8 + w;
  const int b = blockIdx.x >> 7;
  const int it = node & (NG - 1);
  const float* pg = pos + (size_t)b * (NG * 3);

  { uint4 z = {0, 0, 0, 0}; *(uint4*)&bins[w][lane * 4] = z; }
  if (lane == 0) cnt[w] = 0u;

  for (int s = t; s < NG; s += 512) {
    pls[0 * NG + s] = pg[(size_t)s * 3 + 0];
    pls[1 * NG + s] = pg[(size_t)s * 3 + 1];
    pls[2 * NG + s] = pg[(size_t)s * 3 + 2];
  }
  __syncthreads();

  const float px = pls[0 * NG + it];
  const float py = pls[1 * NG + it];
  const float pz = pls[2 * NG + it];

  float vv[16];
  #pragma unroll
  for (int st = 0; st < 16; ++st) {
    const int s = st * 64 + lane;
    const float dx = px - pls[0 * NG + s];
    const float dy = py - pls[1 * NG + s];
    const float dz = pz - pls[2 * NG + s];
    float d2 = dx * dx;
    d2 = fmaf(dy, dy, d2);
    d2 = fmaf(dz, dz, d2);
    if (s == it) d2 += 1e10f;
    const float v = -d2;
    vv[st] = v;
    atomicAdd(&bins[w][vbin_knn(v)], 1u);
  }
  LDS_WAIT();

  const uint4 c4 = *(const uint4*)&bins[w][lane * 4];
  const uint32_t lsum = c4.x + c4.y + c4.z + c4.w;
  uint32_t xs = lsum;
  #pragma unroll
  for (int off = 1; off < 64; off <<= 1) {
    uint32_t tt = (uint32_t)__shfl_down((int)xs, off, 64);
    if (lane + off < 64) xs += tt;
  }
  const uint32_t after = xs - lsum;
  const uint32_t s3 = c4.w + after;
  const uint32_t s2 = c4.z + s3;
  const uint32_t s1 = c4.y + s2;
  const uint32_t s0 = c4.x + s1;
  int localB = -1;
  if (s3 >= 16u) localB = lane * 4 + 3;
  else if (s2 >= 16u) localB = lane * 4 + 2;
  else if (s1 >= 16u) localB = lane * 4 + 1;
  else if (s0 >= 16u) localB = lane * 4 + 0;
  const unsigned long long msk = __ballot(localB >= 0);
  const int hl = 63 - __builtin_clzll(msk);
  const int B = __shfl(localB, hl, 64);

  #pragma unroll
  for (int st = 0; st < 16; ++st) {
    if (vbin_knn(vv[st]) >= B) {
      const uint32_t pos = atomicAdd(&cnt[w], 1u);
      if (pos < 48u) { cv[w][pos] = vv[st]; cidx[w][pos] = st * 64 + lane; }
    }
  }
  LDS_WAIT();

  int C = (int)cnt[w]; if (C > 48) C = 48;
  const float mvv = (lane < C) ? cv[w][lane] : 0.f;
  const int   mii = (lane < C) ? cidx[w][lane] : 0;
  int rank = 0;
  for (int j = 0; j < C; ++j) {
    const float vj = cv[w][j];
    const int ij = cidx[w][j];
    if (vj > mvv || (vj == mvv && ij < mii)) ++rank;
  }
  if (lane < C && rank < 16) o16i[w][rank] = mii;
  LDS_WAIT();

  if (lane < 16) {
    const size_t base = (size_t)node * KK + lane;
    out[4 * (size_t)NSOFT + base] = (float)(b * NG + o16i[w][lane]);
    out[6 * (size_t)NSOFT + base] = (float)node;
  }
}

extern "C" void kernel_launch(void* const* d_in, const int* in_sizes, int n_in,
                              void* d_out, int out_size, void* d_ws, size_t ws_size,
                              hipStream_t stream) {
  const float* x     = (const float*)d_in[0];
  const float* pos   = (const float*)d_in[1];
  const float* W1    = (const float*)d_in[2];
  const float* b1    = (const float*)d_in[3];
  const float* gamma = (const float*)d_in[4];
  const float* beta  = (const float*)d_in[5];
  const float* W2    = (const float*)d_in[6];
  const float* b2    = (const float*)d_in[7];
  const float* t     = (const float*)d_in[8];
  float* out = (float*)d_out;

  float* ws    = (float*)d_ws;
  float* h     = ws;                              // 65536*128
  float* e     = h + (size_t)NNODE * CC;          // 65536*10
  float* p1    = e + (size_t)NNODE * 10;          // 128*1024
  float* p2    = p1 + 128 * 1024;                 // 128*1024
  float* scale = p2 + 128 * 1024;                 // 128
  float* shift = scale + CC;                      // 128

  // key(42) = (0,42); partitionable split -> k1, k2
  uint32_t k1a, k1b, k2a, k2b;
  tf2x32(0u, 42u, 0u, 0u, k1a, k1b);
  tf2x32(0u, 42u, 0u, 1u, k2a, k2b);

  k_gemm1<<<dim3(NNODE / 64), dim3(256), 0, stream>>>(x, W1, b1, h, p1, p2);
  k_bn_final<<<dim3(CC), dim3(256), 0, stream>>>(p1, p2, gamma, beta, scale, shift);
  k_emb<<<dim3(NNODE / 64), dim3(256), 0, stream>>>(h, scale, shift, W2, b2, e, k1a, k1b);
  k_knn<<<dim3(NNODE / 8), dim3(512), 0, stream>>>(pos, out);
  k_soft<<<dim3(NNODE / 8), dim3(512), 0, stream>>>(e, t, out, k2a, k2b);
}